// Round 12
// baseline (131.716 us; speedup 1.0000x reference)
//
#include <hip/hip_runtime.h>

// Radon transform, MI355X. B=4, IMG=256, NA=512.
// R12: FULL batch amortization. f16x8 LDS words = {b0,b1,b2,b3} x (r,r+1):
// one coordinate computation serves 4 samples (R11 served 2). Taps = 2x
// ds_read_b128 at one address (imm offsets 0/176). 8-row slabs keep LDS at
// 45.8 KB -> 3 blocks/CU (24 waves). 2048 blocks (128 angle-groups x 16
// band-groups, 2 slabs each) pack 8/CU in rounds 3+3+2. ws stays 16.8 MB:
// 16 band-groups -> 8 slots via 2-writer coalesced atomicAdd over a
// memset-zeroed buffer. Per-angle geometry hoisted out of the slab loop.

typedef _Float16 f16;
typedef _Float16 f16x2 __attribute__((ext_vector_type(2)));
typedef _Float16 f16x8 __attribute__((ext_vector_type(8)));
typedef __fp16   h16x2 __attribute__((ext_vector_type(2)));
typedef float    f32x2 __attribute__((ext_vector_type(2)));

#define NR    11                 // slab-axis stride in words (Ri 0..9 used, 10 pad)
#define NRW   10                 // written pair-rows per slab
#define NCX   260                // cols X' = 0..259 (col value X'-2)
#define NWRD  (NCX * NR)         // 2860 f16x8 words = 45,760 B -> 3 blocks/CU

// one h-step, ALL 4 batches. Word (X',Ri) = 4 batches x slab-rows (r,r+1) at
// col c=X'-2, r=rbase+Ri. Words e,e+NR = cols c,c+1 -> 2x ds_read_b128, one
// vaddr. Col lerp packed f16x8; slab-axis lerp via 4x fdot2. pc>=0.99 so
// trunc==floor; med3 on pr absorbs band-edge drift into zero/low-weight taps.
#define SAMP4(POS, A0, A1, A2, A3) do {                           \
    float pc_ = (POS).x;                                          \
    float pr_ = __builtin_amdgcn_fmed3f((POS).y, 0.0f, 9.999f);   \
    int   Xi_ = (int)pc_;                                         \
    int   Ri_ = (int)pr_;                                         \
    float wc_ = __builtin_amdgcn_fractf(pc_);                     \
    float wr_ = __builtin_amdgcn_fractf(pr_);                     \
    int   e_  = Xi_ * NR + Ri_;                                   \
    f16x8 lo_ = ldsQ[e_];                                         \
    f16x8 hi_ = ldsQ[e_ + NR];                                    \
    f16x2 w2_ = __builtin_bit_cast(f16x2, __builtin_amdgcn_cvt_pkrtz(wc_, wc_)); \
    f16x8 w8_ = __builtin_shufflevector(w2_, w2_, 0,1,0,1,0,1,0,1); \
    f16x8 t_  = lo_ + w8_ * (hi_ - lo_);                          \
    h16x2 wr2_ = __builtin_amdgcn_cvt_pkrtz(1.0f - wr_, wr_);     \
    (A0) = __builtin_amdgcn_fdot2(__builtin_bit_cast(h16x2, __builtin_shufflevector(t_, t_, 0, 1)), wr2_, (A0), false); \
    (A1) = __builtin_amdgcn_fdot2(__builtin_bit_cast(h16x2, __builtin_shufflevector(t_, t_, 2, 3)), wr2_, (A1), false); \
    (A2) = __builtin_amdgcn_fdot2(__builtin_bit_cast(h16x2, __builtin_shufflevector(t_, t_, 4, 5)), wr2_, (A2), false); \
    (A3) = __builtin_amdgcn_fdot2(__builtin_bit_cast(h16x2, __builtin_shufflevector(t_, t_, 6, 7)), wr2_, (A3), false); \
} while (0)

__global__ __launch_bounds__(512, 6) void radon_k(const float* __restrict__ img,
                                                  float* __restrict__ ws2) {
    __shared__ f16x8 ldsQ[NWRD];
    const int tid = threadIdx.x;
    const int bx  = blockIdx.x;               // 2048 = g(128) x Q2(16)
    const int Q2 = bx & 15, g = bx >> 4;      // g: 4-angle group
    const bool colC = (g >= 32) && (g < 96);  // a in [128,384): column slabs
    const int w = tid & 255, sub = tid >> 8;  // angle uniform per wave
    const float xw = (float)w - 127.5f;

    // ---- hoisted per-angle geometry (2 angles per thread)
    float csA[2], AsA[2], rsA[2], ArA[2], ivA[2];
    int hx0A[2], hx1A[2];
#pragma unroll
    for (int k = 0; k < 2; ++k) {
        const int a = (g << 2) | (k << 1) | sub;
        const float th = (float)a * 6.1359231515425649e-3f;   // a*pi/512
        const float sth = __sinf(th), cth = __cosf(th);       // block-consistent
        const float Ax = fmaf(cth, xw, fmaf(sth, -127.5f, 127.5f));
        const float Ay = fmaf(-sth, xw, fmaf(cth, -127.5f, 127.5f));
        float cs, As, rs, Ar;                 // col coord / slab coord roles
        if (colC) { cs = cth; As = Ay; rs = sth; Ar = Ax; }
        else      { cs = sth; As = Ax; rs = cth; Ar = Ay; }
        csA[k] = cs; AsA[k] = As; rsA[k] = rs; ArA[k] = Ar;
        ivA[k] = 1.0f / rs;                   // |rs| >= 0.707
        // col validity v(h)=As+h*cs in (-1,256); cs signed, may be ~0
        int hx0 = 0, hx1 = 255;
        if (cs != 0.f) {
            const float invc = 1.0f / cs;
            float ta = (-1.0f - As) * invc, tb = (256.0f - As) * invc;
            ta = fmaxf(fminf(ta, 400.f), -400.f);
            tb = fmaxf(fminf(tb, 400.f), -400.f);
            if (cs > 0.f) { hx0 = max(0, (int)ceilf(ta));      hx1 = min(255, (int)ceilf(tb) - 1); }
            else          { hx0 = max(0, (int)floorf(tb) + 1); hx1 = min(255, (int)floorf(ta)); }
        } else if (As <= -1.f || As >= 256.f) {
            hx1 = -1;                         // constant col coord, out of range
        }
        hx0A[k] = hx0; hx1A[k] = hx1;
    }

    float acc[2][4] = {{0.f,0.f,0.f,0.f},{0.f,0.f,0.f,0.f}};

    for (int s = 0; s < 2; ++s) {
        const int q = (Q2 << 1) | s;          // 8-row band 0..31
        const int rbase = (q << 3) - 1;       // staged pair-rows rbase..rbase+10
        if (s) __syncthreads();               // drain slab-0 compute

        // ---- stage 4-batch interleaved words (2600 items)
        for (int u = tid; u < NCX * NRW; u += 512) {
            int Xp, Ri, p0, p1; bool ok0, ok1;
            if (!colC) {                      // slab axis = image row; X' fastest
                Ri = u / NCX; Xp = u - Ri * NCX;
                int r0 = rbase + Ri, c = Xp - 2;
                bool cv = (unsigned)c < 256u;
                ok0 = cv && ((unsigned)r0 < 256u);
                ok1 = cv && ((unsigned)(r0 + 1) < 256u);
                p0 = (r0 << 8) + c; p1 = p0 + 256;
            } else {                          // slab axis = image col; Ri fastest
                Xp = u / NRW; Ri = u - Xp * NRW;
                int c0 = rbase + Ri, r = Xp - 2;
                bool rv = (unsigned)r < 256u;
                ok0 = rv && ((unsigned)c0 < 256u);
                ok1 = rv && ((unsigned)(c0 + 1) < 256u);
                p0 = (r << 8) + c0; p1 = p0 + 1;
            }
            float v00=0.f,v01=0.f,v10=0.f,v11=0.f,v20=0.f,v21=0.f,v30=0.f,v31=0.f;
            if (ok0) {
                v00 = img[p0];             v10 = img[p0 + (1 << 16)];
                v20 = img[p0 + (2 << 16)]; v30 = img[p0 + (3 << 16)];
            }
            if (ok1) {
                v01 = img[p1];             v11 = img[p1 + (1 << 16)];
                v21 = img[p1 + (2 << 16)]; v31 = img[p1 + (3 << 16)];
            }
            uint4 pk;
            pk.x = __builtin_bit_cast(unsigned, __builtin_amdgcn_cvt_pkrtz(v00, v01));
            pk.y = __builtin_bit_cast(unsigned, __builtin_amdgcn_cvt_pkrtz(v10, v11));
            pk.z = __builtin_bit_cast(unsigned, __builtin_amdgcn_cvt_pkrtz(v20, v21));
            pk.w = __builtin_bit_cast(unsigned, __builtin_amdgcn_cvt_pkrtz(v30, v31));
            ((uint4*)ldsQ)[Xp * NR + Ri] = pk;
        }
        __syncthreads();

        // band [B0,B1) on the slab axis; adjacent q share identical floats
        const float B0 = (q == 0)  ? -1.0f  : (float)(q << 3);
        const float B1 = (q == 31) ? 256.0f : (float)((q + 1) << 3);

#pragma unroll
        for (int k = 0; k < 2; ++k) {
            const float cs = csA[k], As = AsA[k], rs = rsA[k];
            const float Ar = ArA[k], invr = ivA[k];
            const float tA = (B0 - Ar) * invr, tB = (B1 - Ar) * invr;
            int h0, h1;
            if (rs > 0.f) { h0 = (int)ceilf(tA);      h1 = (int)ceilf(tB) - 1; }
            else          { h0 = (int)floorf(tB) + 1; h1 = (int)floorf(tA); }
            h0 = max(h0, hx0A[k]); h1 = min(h1, hx1A[k]);
            if (h0 <= h1) {
                const float h0f = (float)h0;
                f32x2 pos0, st;
                pos0.x = fmaf(h0f, cs, As + 2.0f);           // col coord + 2
                pos0.y = fmaf(h0f, rs, Ar - (float)rbase);   // slab-local coord
                st.x = cs; st.y = rs;
                f32x2 pA = pos0, pB = pos0 + st;
                const f32x2 st2 = st + st;
                float a0=0.f,a1=0.f,a2=0.f,a3=0.f, b0=0.f,b1=0.f,b2=0.f,b3=0.f;
                const int n = h1 - h0 + 1;                   // <= 13
                int i = 0;
                for (; i + 2 <= n; i += 2) {                 // dual h-chains
                    SAMP4(pA, a0, a1, a2, a3);
                    SAMP4(pB, b0, b1, b2, b3);
                    pA += st2; pB += st2;
                }
                if (i < n) SAMP4(pA, a0, a1, a2, a3);
                acc[k][0] += a0 + b0; acc[k][1] += a1 + b1;
                acc[k][2] += a2 + b2; acc[k][3] += a3 + b3;
            }
        }
    }

    // ---- 2 writers per slot (Q2 and Q2^1) -> coalesced atomicAdd into
    // memset-zeroed ws[slot][b][a][w], slot = Q2>>1 in 0..7
    const int slot = Q2 >> 1;
#pragma unroll
    for (int k = 0; k < 2; ++k) {
        const int a = (g << 2) | (k << 1) | sub;
#pragma unroll
        for (int b = 0; b < 4; ++b)
            atomicAdd(ws2 + ((((slot << 2) + b) << 9) | a) * 256 + w, acc[k][b]);
    }
}

__global__ __launch_bounds__(256) void reduce_k(const float* __restrict__ ws2,
                                                float* __restrict__ out) {
    __shared__ float s[32][33];
    const int bx = blockIdx.x;                // 512 = b(4) x at(16) x wt(8)
    const int wt = bx & 7, at = (bx >> 3) & 15, b = bx >> 7;
    const int a0 = at << 5, w0 = wt << 5;
    const int wl = threadIdx.x & 31, r8 = threadIdx.x >> 5;
#pragma unroll
    for (int p = 0; p < 4; ++p) {
        int ar = r8 + (p << 3);
        int a  = a0 + ar;
        float acc = 0.f;
#pragma unroll
        for (int qq = 0; qq < 8; ++qq)
            acc += ws2[(((((qq << 2) + b) << 9) | a) << 8) | (w0 + wl)];
        s[ar][wl] = acc;                      // s[a_local][w_local]
    }
    __syncthreads();
#pragma unroll
    for (int p = 0; p < 4; ++p) {
        int wr = r8 + (p << 3);
        out[(b << 17) | ((w0 + wr) << 9) | (a0 + wl)] = s[wl][wr];  // coalesced in a
    }
}

extern "C" void kernel_launch(void* const* d_in, const int* in_sizes, int n_in,
                              void* d_out, int out_size, void* d_ws, size_t ws_size,
                              hipStream_t stream) {
    const float* img = (const float*)d_in[0];
    float* out = (float*)d_out;
    float* ws2 = (float*)d_ws;                // 16.8 MB: [slot8][b][a][w]
    hipMemsetAsync(ws2, 0, (size_t)8 * 4 * 512 * 256 * 4, stream);
    radon_k <<<dim3(2048), dim3(512), 0, stream>>>(img, ws2);
    reduce_k<<<dim3(512),  dim3(256), 0, stream>>>(ws2, out);
}

// Round 13
// 129.745 us; speedup vs baseline: 1.0152x; 1.0152x over previous
//
#include <hip/hip_runtime.h>

// Radon transform, MI355X. B=4, IMG=256, NA=512.
// R13 = R11 + edge<->center band pairing. R11/R12 were flat at radon~75us with
// Occupancy~50% despite a 32-wave/CU config: 1024 blocks = ONE co-resident
// cohort, so duration = max block time, and band work is unimodal in q
// (central bands ~2x edge bands at diagonal angles). Pairing slab q2 with
// q2+8 makes per-block work ~constant -> cohort drains together.
// Everything else identical to R11: batch-interleaved f16x4 LDS words
// (ds_read2_b64 per dual-batch sample), 39.5 KB -> 4 blocks/CU, triple
// h-chains, ws[slot][b][a][w] partials + transpose-reduce.

typedef _Float16 f16;
typedef _Float16 f16x2 __attribute__((ext_vector_type(2)));
typedef _Float16 f16x4 __attribute__((ext_vector_type(4)));
typedef __fp16   h16x2 __attribute__((ext_vector_type(2)));
typedef float    f32x2 __attribute__((ext_vector_type(2)));

#define NR    19                 // padded slab-axis stride (Ri 0..17 used)
#define NRW   18                 // written slab-pair rows
#define NCX   260                // cols X' = 0..259 (col-axis value X'-2)
#define NWRD  (NCX * NR)         // 4940 f16x4 words = 39,520 B -> 4 blocks/CU

#define SAMP2(POS, A0, A1) do {                                   \
    float pc_ = (POS).x;                                          \
    float pr_ = __builtin_amdgcn_fmed3f((POS).y, 0.0f, 17.999f);  \
    int   Xi_ = (int)pc_;                                         \
    int   Ri_ = (int)pr_;                                         \
    float wc_ = __builtin_amdgcn_fractf(pc_);                     \
    float wr_ = __builtin_amdgcn_fractf(pr_);                     \
    int   e_  = Xi_ * NR + Ri_;                                   \
    f16x4 lo_ = ldsQ[e_];                                         \
    f16x4 hi_ = ldsQ[e_ + NR];                                    \
    f16x2 wc2_ = __builtin_bit_cast(f16x2, __builtin_amdgcn_cvt_pkrtz(wc_, wc_)); \
    f16x4 wc4_ = __builtin_shufflevector(wc2_, wc2_, 0, 1, 0, 1); \
    f16x4 t_   = lo_ + wc4_ * (hi_ - lo_);                        \
    h16x2 wr2_ = __builtin_amdgcn_cvt_pkrtz(1.0f - wr_, wr_);     \
    h16x2 t0_  = __builtin_bit_cast(h16x2, __builtin_shufflevector(t_, t_, 0, 1)); \
    h16x2 t1_  = __builtin_bit_cast(h16x2, __builtin_shufflevector(t_, t_, 2, 3)); \
    (A0) = __builtin_amdgcn_fdot2(t0_, wr2_, (A0), false);        \
    (A1) = __builtin_amdgcn_fdot2(t1_, wr2_, (A1), false);        \
} while (0)

__global__ __launch_bounds__(512, 8) void radon_k(const float* __restrict__ img,
                                                  float* __restrict__ ws2) {
    __shared__ f16x4 ldsQ[NWRD];
    const int tid = threadIdx.x;
    const int bx  = blockIdx.x;                 // 1024 = bp(2) x g(64) x q2(8)
    const int q2 = bx & 7, g = (bx >> 3) & 63, bp = bx >> 9;
    const bool colC = (g >= 16) && (g < 48);    // a in [128,384): column slabs
    const float* src0 = img + ((bp << 1) << 16);
    const float* src1 = img + (((bp << 1) | 1) << 16);

    const int   w   = tid & 255, sub = tid >> 8;  // angle uniform per wave
    const float xw  = (float)w - 127.5f;

    // hoisted per-angle trig (same for both slabs)
    float sv[4], cv[4];
#pragma unroll
    for (int k = 0; k < 4; ++k) {
        const int a = (g << 3) | (k << 1) | sub;
        const float th = (float)a * 6.1359231515425649e-3f;   // a*pi/512
        sv[k] = __sinf(th); cv[k] = __cosf(th);               // block-consistent
    }

    float accA[4] = {0.f, 0.f, 0.f, 0.f};       // batch bp*2
    float accB[4] = {0.f, 0.f, 0.f, 0.f};       // batch bp*2+1

    for (int s = 0; s < 2; ++s) {
        // R13 band pairing: slab q2 (s=0) then q2+8 (s=1). Work(q) is unimodal
        // in q, so the pair sum is ~constant across blocks -> balanced cohort.
        const int q = q2 | (s << 3);            // slab 0..15 (16 rows each)
        const int rbase = (q << 4) - 1;         // slab-axis pairs rbase..rbase+18
        if (s) __syncthreads();                 // drain slab-0 compute

        // ---- stage interleaved words for both batches
        if (!colC) {
            // row-mode: slab axis = image row. X' fastest -> 4 coalesced streams
            for (int u = tid; u < NCX * NRW; u += 512) {
                int Ri = u / NCX;               // 0..17
                int Xp = u - Ri * NCX;          // 0..259
                int r0 = rbase + Ri;
                int c  = Xp - 2;
                float v00 = 0.f, v01 = 0.f, v10 = 0.f, v11 = 0.f;
                if ((unsigned)c < 256u) {
                    if ((unsigned)r0 < 256u) {
                        v00 = src0[(r0 << 8) + c];
                        v10 = src1[(r0 << 8) + c];
                    }
                    if ((unsigned)(r0 + 1) < 256u) {
                        v01 = src0[((r0 + 1) << 8) + c];
                        v11 = src1[((r0 + 1) << 8) + c];
                    }
                }
                uint2 pk;
                pk.x = __builtin_bit_cast(unsigned, __builtin_amdgcn_cvt_pkrtz(v00, v01));
                pk.y = __builtin_bit_cast(unsigned, __builtin_amdgcn_cvt_pkrtz(v10, v11));
                ((uint2*)ldsQ)[Xp * NR + Ri] = pk;
            }
        } else {
            // col-mode: slab axis = image column; Ri fastest so lanes read
            // ~19 consecutive floats per image row
            for (int u = tid; u < NCX * NRW; u += 512) {
                int Xp = u / NRW;               // 0..259 (image row r = Xp-2)
                int Ri = u - Xp * NRW;          // 0..17  (image col c0 = rbase+Ri)
                int r  = Xp - 2;
                int c0 = rbase + Ri;
                float v00 = 0.f, v01 = 0.f, v10 = 0.f, v11 = 0.f;
                if ((unsigned)r < 256u) {
                    const float* rp0 = src0 + (r << 8);
                    const float* rp1 = src1 + (r << 8);
                    if ((unsigned)c0 < 256u)       { v00 = rp0[c0];     v10 = rp1[c0]; }
                    if ((unsigned)(c0 + 1) < 256u) { v01 = rp0[c0 + 1]; v11 = rp1[c0 + 1]; }
                }
                uint2 pk;
                pk.x = __builtin_bit_cast(unsigned, __builtin_amdgcn_cvt_pkrtz(v00, v01));
                pk.y = __builtin_bit_cast(unsigned, __builtin_amdgcn_cvt_pkrtz(v10, v11));
                ((uint2*)ldsQ)[Xp * NR + Ri] = pk;
            }
        }
        __syncthreads();

        // band [B0,B1) on the slab axis; adjacent q share identical floats
        const float B0 = (q == 0)  ? -1.0f  : (float)(q << 4);
        const float B1 = (q == 15) ? 256.0f : (float)((q << 4) + 16);

#pragma unroll
        for (int k = 0; k < 4; ++k) {
            const float sth = sv[k], cth = cv[k];
            const float Ax = fmaf(cth, xw, fmaf(sth, -127.5f, 127.5f));
            const float Ay = fmaf(-sth, xw, fmaf(cth, -127.5f, 127.5f));
            float cs, As, rs, Ar;                // col coord / slab coord roles
            if (colC) { cs = cth; As = Ay; rs = sth; Ar = Ax; }
            else      { cs = sth; As = Ax; rs = cth; Ar = Ay; }

            // slab ownership: r(h)=Ar+h*rs in [B0,B1); |rs|>=0.707; exact
            // ceil/floor partition (adjacent q share identical boundary floats)
            const float invr = 1.0f / rs;
            const float tA = (B0 - Ar) * invr, tB = (B1 - Ar) * invr;
            int h0, h1;
            if (rs > 0.f) { h0 = (int)ceilf(tA);      h1 = (int)ceilf(tB) - 1; }
            else          { h0 = (int)floorf(tB) + 1; h1 = (int)floorf(tA);   }

            // col validity v(h)=As+h*cs in (-1,256); cs signed, may be ~0
            if (cs != 0.f) {
                const float invc = 1.0f / cs;
                float ta = (-1.0f - As) * invc, tb = (256.0f - As) * invc;
                ta = fmaxf(fminf(ta, 400.f), -400.f);
                tb = fmaxf(fminf(tb, 400.f), -400.f);
                if (cs > 0.f) { h0 = max(h0, (int)ceilf(ta));      h1 = min(h1, (int)ceilf(tb) - 1); }
                else          { h0 = max(h0, (int)floorf(tb) + 1); h1 = min(h1, (int)floorf(ta));   }
            } else if (As <= -1.f || As >= 256.f) {
                h1 = h0 - 1;
            }
            h0 = max(h0, 0); h1 = min(h1, 255);

            if (h0 <= h1) {
                const float h0f = (float)h0;
                f32x2 pos0, st;
                pos0.x = fmaf(h0f, cs, As + 2.0f);           // col coord + 2
                pos0.y = fmaf(h0f, rs, Ar - (float)rbase);   // slab-local coord
                st.x = cs; st.y = rs;
                f32x2 pA = pos0, pB = pos0 + st, pC = pB + st;
                const f32x2 st3 = st + st + st;
                float a00 = 0.f, a01 = 0.f, a10 = 0.f, a11 = 0.f, a20 = 0.f, a21 = 0.f;
                const int n = h1 - h0 + 1;                   // <= 24
                int i = 0;
                for (; i + 3 <= n; i += 3) {                 // triple h-chains
                    SAMP2(pA, a00, a01);
                    SAMP2(pB, a10, a11);
                    SAMP2(pC, a20, a21);
                    pA += st3; pB += st3; pC += st3;
                }
                if (i + 1 <= n) SAMP2(pA, a00, a01);
                if (i + 2 <= n) SAMP2(pB, a10, a11);
                accA[k] += a00 + a10 + a20;
                accB[k] += a01 + a11 + a21;
            }
        }
    }

#pragma unroll
    for (int k = 0; k < 4; ++k) {               // wave-coalesced 256B segments
        const int a  = (g << 3) | (k << 1) | sub;
        const int b0 = bp << 1;
        ws2[((((q2 << 2) + b0) << 9) | a) * 256 + w]     = accA[k];
        ws2[((((q2 << 2) + b0 + 1) << 9) | a) * 256 + w] = accB[k];
    }
}

__global__ __launch_bounds__(256) void reduce_k(const float* __restrict__ ws2,
                                                float* __restrict__ out) {
    __shared__ float s[32][33];
    const int bx = blockIdx.x;                  // 512 = b(4) x at(16) x wt(8)
    const int wt = bx & 7, at = (bx >> 3) & 15, b = bx >> 7;
    const int a0 = at << 5, w0 = wt << 5;
    const int wl = threadIdx.x & 31, r8 = threadIdx.x >> 5;
#pragma unroll
    for (int p = 0; p < 4; ++p) {
        int ar = r8 + (p << 3);
        int a  = a0 + ar;
        float acc = 0.f;
#pragma unroll
        for (int qq = 0; qq < 8; ++qq)
            acc += ws2[(((((qq << 2) + b) << 9) | a) << 8) | (w0 + wl)];
        s[ar][wl] = acc;                        // s[a_local][w_local]
    }
    __syncthreads();
#pragma unroll
    for (int p = 0; p < 4; ++p) {
        int wr = r8 + (p << 3);
        out[(b << 17) | ((w0 + wr) << 9) | (a0 + wl)] = s[wl][wr];  // coalesced in a
    }
}

extern "C" void kernel_launch(void* const* d_in, const int* in_sizes, int n_in,
                              void* d_out, int out_size, void* d_ws, size_t ws_size,
                              hipStream_t stream) {
    const float* img = (const float*)d_in[0];
    float* out = (float*)d_out;
    float* ws2 = (float*)d_ws;                  // 16.8 MB: [q2][b][a][w]
    radon_k <<<dim3(1024), dim3(512), 0, stream>>>(img, ws2);
    reduce_k<<<dim3(512),  dim3(256), 0, stream>>>(ws2, out);
}

// Round 14
// 123.638 us; speedup vs baseline: 1.0653x; 1.0494x over previous
//
#include <hip/hip_runtime.h>

// Radon transform, MI355X. B=4, IMG=256, NA=512.
// R14 = R13 radon core + fused reduction. The 8 q2-writers atomicAdd into a
// w-contiguous 2MB accumulator acc[b][a][w] (wave-atomic = one 256B segment,
// 8 writers/line — NOT R0's out[b][w][a] 64-line scatter), memset-zeroed;
// a pure transpose kernel then emits out[b][w][a]. Removes 33.6 MB of ws
// round-trip + the 8-way reduce. Per-angle geometry (Ax/Ay/roles/invr/
// col-validity) hoisted out of the slab loop (R13 recomputed it 8x vs 4x).

typedef _Float16 f16;
typedef _Float16 f16x2 __attribute__((ext_vector_type(2)));
typedef _Float16 f16x4 __attribute__((ext_vector_type(4)));
typedef __fp16   h16x2 __attribute__((ext_vector_type(2)));
typedef float    f32x2 __attribute__((ext_vector_type(2)));

#define NR    19                 // padded slab-axis stride (Ri 0..17 used)
#define NRW   18                 // written slab-pair rows
#define NCX   260                // cols X' = 0..259 (col-axis value X'-2)
#define NWRD  (NCX * NR)         // 4940 f16x4 words = 39,520 B -> 4 blocks/CU

#define SAMP2(POS, A0, A1) do {                                   \
    float pc_ = (POS).x;                                          \
    float pr_ = __builtin_amdgcn_fmed3f((POS).y, 0.0f, 17.999f);  \
    int   Xi_ = (int)pc_;                                         \
    int   Ri_ = (int)pr_;                                         \
    float wc_ = __builtin_amdgcn_fractf(pc_);                     \
    float wr_ = __builtin_amdgcn_fractf(pr_);                     \
    int   e_  = Xi_ * NR + Ri_;                                   \
    f16x4 lo_ = ldsQ[e_];                                         \
    f16x4 hi_ = ldsQ[e_ + NR];                                    \
    f16x2 wc2_ = __builtin_bit_cast(f16x2, __builtin_amdgcn_cvt_pkrtz(wc_, wc_)); \
    f16x4 wc4_ = __builtin_shufflevector(wc2_, wc2_, 0, 1, 0, 1); \
    f16x4 t_   = lo_ + wc4_ * (hi_ - lo_);                        \
    h16x2 wr2_ = __builtin_amdgcn_cvt_pkrtz(1.0f - wr_, wr_);     \
    h16x2 t0_  = __builtin_bit_cast(h16x2, __builtin_shufflevector(t_, t_, 0, 1)); \
    h16x2 t1_  = __builtin_bit_cast(h16x2, __builtin_shufflevector(t_, t_, 2, 3)); \
    (A0) = __builtin_amdgcn_fdot2(t0_, wr2_, (A0), false);        \
    (A1) = __builtin_amdgcn_fdot2(t1_, wr2_, (A1), false);        \
} while (0)

__global__ __launch_bounds__(512, 8) void radon_k(const float* __restrict__ img,
                                                  float* __restrict__ accW) {
    __shared__ f16x4 ldsQ[NWRD];
    const int tid = threadIdx.x;
    const int bx  = blockIdx.x;                 // 1024 = bp(2) x g(64) x q2(8)
    const int q2 = bx & 7, g = (bx >> 3) & 63, bp = bx >> 9;
    const bool colC = (g >= 16) && (g < 48);    // a in [128,384): column slabs
    const float* src0 = img + ((bp << 1) << 16);
    const float* src1 = img + (((bp << 1) | 1) << 16);

    const int   w   = tid & 255, sub = tid >> 8;  // angle uniform per wave
    const float xw  = (float)w - 127.5f;

    // ---- hoisted per-angle geometry (band-independent)
    float csA[4], AsA[4], rsA[4], ArA[4], ivA[4];
    int   hx0A[4], hx1A[4];
#pragma unroll
    for (int k = 0; k < 4; ++k) {
        const int a = (g << 3) | (k << 1) | sub;
        const float th = (float)a * 6.1359231515425649e-3f;   // a*pi/512
        const float sth = __sinf(th), cth = __cosf(th);       // block-consistent
        const float Ax = fmaf(cth, xw, fmaf(sth, -127.5f, 127.5f));
        const float Ay = fmaf(-sth, xw, fmaf(cth, -127.5f, 127.5f));
        float cs, As, rs, Ar;                   // col coord / slab coord roles
        if (colC) { cs = cth; As = Ay; rs = sth; Ar = Ax; }
        else      { cs = sth; As = Ax; rs = cth; Ar = Ay; }
        csA[k] = cs; AsA[k] = As; rsA[k] = rs; ArA[k] = Ar;
        ivA[k] = 1.0f / rs;                     // |rs| >= 0.707
        // col validity v(h)=As+h*cs in (-1,256); cs signed, may be ~0
        int hx0 = 0, hx1 = 255;
        if (cs != 0.f) {
            const float invc = 1.0f / cs;
            float ta = (-1.0f - As) * invc, tb = (256.0f - As) * invc;
            ta = fmaxf(fminf(ta, 400.f), -400.f);
            tb = fmaxf(fminf(tb, 400.f), -400.f);
            if (cs > 0.f) { hx0 = max(0, (int)ceilf(ta));      hx1 = min(255, (int)ceilf(tb) - 1); }
            else          { hx0 = max(0, (int)floorf(tb) + 1); hx1 = min(255, (int)floorf(ta)); }
        } else if (As <= -1.f || As >= 256.f) {
            hx1 = -1;                           // constant col coord, out of range
        }
        hx0A[k] = hx0; hx1A[k] = hx1;
    }

    float accA[4] = {0.f, 0.f, 0.f, 0.f};       // batch bp*2
    float accB[4] = {0.f, 0.f, 0.f, 0.f};       // batch bp*2+1

    for (int s = 0; s < 2; ++s) {
        // band pairing: slab q2 then q2+8 (kept from R13; harmless)
        const int q = q2 | (s << 3);            // slab 0..15 (16 rows each)
        const int rbase = (q << 4) - 1;         // slab-axis pairs rbase..rbase+18
        if (s) __syncthreads();                 // drain slab-0 compute

        // ---- stage interleaved words for both batches
        if (!colC) {
            // row-mode: slab axis = image row. X' fastest -> 4 coalesced streams
            for (int u = tid; u < NCX * NRW; u += 512) {
                int Ri = u / NCX;               // 0..17
                int Xp = u - Ri * NCX;          // 0..259
                int r0 = rbase + Ri;
                int c  = Xp - 2;
                float v00 = 0.f, v01 = 0.f, v10 = 0.f, v11 = 0.f;
                if ((unsigned)c < 256u) {
                    if ((unsigned)r0 < 256u) {
                        v00 = src0[(r0 << 8) + c];
                        v10 = src1[(r0 << 8) + c];
                    }
                    if ((unsigned)(r0 + 1) < 256u) {
                        v01 = src0[((r0 + 1) << 8) + c];
                        v11 = src1[((r0 + 1) << 8) + c];
                    }
                }
                uint2 pk;
                pk.x = __builtin_bit_cast(unsigned, __builtin_amdgcn_cvt_pkrtz(v00, v01));
                pk.y = __builtin_bit_cast(unsigned, __builtin_amdgcn_cvt_pkrtz(v10, v11));
                ((uint2*)ldsQ)[Xp * NR + Ri] = pk;
            }
        } else {
            // col-mode: slab axis = image column; Ri fastest so lanes read
            // ~19 consecutive floats per image row
            for (int u = tid; u < NCX * NRW; u += 512) {
                int Xp = u / NRW;               // 0..259 (image row r = Xp-2)
                int Ri = u - Xp * NRW;          // 0..17  (image col c0 = rbase+Ri)
                int r  = Xp - 2;
                int c0 = rbase + Ri;
                float v00 = 0.f, v01 = 0.f, v10 = 0.f, v11 = 0.f;
                if ((unsigned)r < 256u) {
                    const float* rp0 = src0 + (r << 8);
                    const float* rp1 = src1 + (r << 8);
                    if ((unsigned)c0 < 256u)       { v00 = rp0[c0];     v10 = rp1[c0]; }
                    if ((unsigned)(c0 + 1) < 256u) { v01 = rp0[c0 + 1]; v11 = rp1[c0 + 1]; }
                }
                uint2 pk;
                pk.x = __builtin_bit_cast(unsigned, __builtin_amdgcn_cvt_pkrtz(v00, v01));
                pk.y = __builtin_bit_cast(unsigned, __builtin_amdgcn_cvt_pkrtz(v10, v11));
                ((uint2*)ldsQ)[Xp * NR + Ri] = pk;
            }
        }
        __syncthreads();

        // band [B0,B1) on the slab axis; adjacent q share identical floats
        const float B0 = (q == 0)  ? -1.0f  : (float)(q << 4);
        const float B1 = (q == 15) ? 256.0f : (float)((q << 4) + 16);

#pragma unroll
        for (int k = 0; k < 4; ++k) {
            const float cs = csA[k], As = AsA[k], rs = rsA[k];
            const float Ar = ArA[k], invr = ivA[k];
            const float tA = (B0 - Ar) * invr, tB = (B1 - Ar) * invr;
            int h0, h1;
            if (rs > 0.f) { h0 = (int)ceilf(tA);      h1 = (int)ceilf(tB) - 1; }
            else          { h0 = (int)floorf(tB) + 1; h1 = (int)floorf(tA);   }
            h0 = max(h0, hx0A[k]); h1 = min(h1, hx1A[k]);

            if (h0 <= h1) {
                const float h0f = (float)h0;
                f32x2 pos0, st;
                pos0.x = fmaf(h0f, cs, As + 2.0f);           // col coord + 2
                pos0.y = fmaf(h0f, rs, Ar - (float)rbase);   // slab-local coord
                st.x = cs; st.y = rs;
                f32x2 pA = pos0, pB = pos0 + st, pC = pB + st;
                const f32x2 st3 = st + st + st;
                float a00 = 0.f, a01 = 0.f, a10 = 0.f, a11 = 0.f, a20 = 0.f, a21 = 0.f;
                const int n = h1 - h0 + 1;                   // <= 24
                int i = 0;
                for (; i + 3 <= n; i += 3) {                 // triple h-chains
                    SAMP2(pA, a00, a01);
                    SAMP2(pB, a10, a11);
                    SAMP2(pC, a20, a21);
                    pA += st3; pB += st3; pC += st3;
                }
                if (i + 1 <= n) SAMP2(pA, a00, a01);
                if (i + 2 <= n) SAMP2(pB, a10, a11);
                accA[k] += a00 + a10 + a20;
                accB[k] += a01 + a11 + a21;
            }
        }
    }

    // ---- fused reduction: coalesced atomics into acc[b][a][w] (w contiguous,
    // 256B per wave-atomic, 8 q2-writers per line)
    const int b0 = bp << 1;
#pragma unroll
    for (int k = 0; k < 4; ++k) {
        const int a = (g << 3) | (k << 1) | sub;
        atomicAdd(accW + ((((b0    ) << 9) | a) << 8) + w, accA[k]);
        atomicAdd(accW + ((((b0 + 1) << 9) | a) << 8) + w, accB[k]);
    }
}

// pure transpose: out[b][w][a] = acc[b][a][w]  (2MB -> 2MB)
__global__ __launch_bounds__(256) void transpose_out(const float* __restrict__ accW,
                                                     float* __restrict__ out) {
    __shared__ float s[32][33];
    const int bx = blockIdx.x;                  // 512 = b(4) x at(16) x wt(8)
    const int wt = bx & 7, at = (bx >> 3) & 15, b = bx >> 7;
    const int a0 = at << 5, w0 = wt << 5;
    const int wl = threadIdx.x & 31, r8 = threadIdx.x >> 5;
#pragma unroll
    for (int p = 0; p < 4; ++p) {
        int ar = r8 + (p << 3);
        s[ar][wl] = accW[(((b << 9) | (a0 + ar)) << 8) | (w0 + wl)];  // coalesced in w
    }
    __syncthreads();
#pragma unroll
    for (int p = 0; p < 4; ++p) {
        int wr = r8 + (p << 3);
        out[(b << 17) | ((w0 + wr) << 9) | (a0 + wl)] = s[wl][wr];    // coalesced in a
    }
}

extern "C" void kernel_launch(void* const* d_in, const int* in_sizes, int n_in,
                              void* d_out, int out_size, void* d_ws, size_t ws_size,
                              hipStream_t stream) {
    const float* img = (const float*)d_in[0];
    float* out  = (float*)d_out;
    float* accW = (float*)d_ws;                 // 2 MB: acc[b][a][w]
    hipMemsetAsync(accW, 0, (size_t)4 * 512 * 256 * 4, stream);
    radon_k      <<<dim3(1024), dim3(512), 0, stream>>>(img, accW);
    transpose_out<<<dim3(512),  dim3(256), 0, stream>>>(accW, out);
}

// Round 15
// 118.269 us; speedup vs baseline: 1.1137x; 1.0454x over previous
//
#include <hip/hip_runtime.h>

// Radon transform, MI355X. B=4, IMG=256, NA=512.
// R15 = R14 with single-band blocks. R11-R14 ran 1024 blocks = exactly one
// co-resident cohort (4/CU): no queued blocks -> every CU idles behind the
// slowest block (Occupancy ~49%, duration = max not mean). Splitting each
// block's two sequential bands into independent blocks gives 2048 blocks =
// 2 cohorts; the scheduler backfills drained slots (R8 at 2048 blocks showed
// 64% occupancy). Same total staging/sample work, same 39.5 KB LDS.
// Core unchanged: batch-interleaved f16x4 words, ds_read2_b64 dual-batch
// samples, hoisted geometry, coalesced atomicAdd into acc[b][a][w] (16
// writers/cell now), pure transpose_out epilogue.

typedef _Float16 f16;
typedef _Float16 f16x2 __attribute__((ext_vector_type(2)));
typedef _Float16 f16x4 __attribute__((ext_vector_type(4)));
typedef __fp16   h16x2 __attribute__((ext_vector_type(2)));
typedef float    f32x2 __attribute__((ext_vector_type(2)));

#define NR    19                 // padded slab-axis stride (Ri 0..17 used)
#define NRW   18                 // written slab-pair rows
#define NCX   260                // cols X' = 0..259 (col-axis value X'-2)
#define NWRD  (NCX * NR)         // 4940 f16x4 words = 39,520 B -> 4 blocks/CU

#define SAMP2(POS, A0, A1) do {                                   \
    float pc_ = (POS).x;                                          \
    float pr_ = __builtin_amdgcn_fmed3f((POS).y, 0.0f, 17.999f);  \
    int   Xi_ = (int)pc_;                                         \
    int   Ri_ = (int)pr_;                                         \
    float wc_ = __builtin_amdgcn_fractf(pc_);                     \
    float wr_ = __builtin_amdgcn_fractf(pr_);                     \
    int   e_  = Xi_ * NR + Ri_;                                   \
    f16x4 lo_ = ldsQ[e_];                                         \
    f16x4 hi_ = ldsQ[e_ + NR];                                    \
    f16x2 wc2_ = __builtin_bit_cast(f16x2, __builtin_amdgcn_cvt_pkrtz(wc_, wc_)); \
    f16x4 wc4_ = __builtin_shufflevector(wc2_, wc2_, 0, 1, 0, 1); \
    f16x4 t_   = lo_ + wc4_ * (hi_ - lo_);                        \
    h16x2 wr2_ = __builtin_amdgcn_cvt_pkrtz(1.0f - wr_, wr_);     \
    h16x2 t0_  = __builtin_bit_cast(h16x2, __builtin_shufflevector(t_, t_, 0, 1)); \
    h16x2 t1_  = __builtin_bit_cast(h16x2, __builtin_shufflevector(t_, t_, 2, 3)); \
    (A0) = __builtin_amdgcn_fdot2(t0_, wr2_, (A0), false);        \
    (A1) = __builtin_amdgcn_fdot2(t1_, wr2_, (A1), false);        \
} while (0)

__global__ __launch_bounds__(512, 8) void radon_k(const float* __restrict__ img,
                                                  float* __restrict__ accW) {
    __shared__ f16x4 ldsQ[NWRD];
    const int tid = threadIdx.x;
    const int bx  = blockIdx.x;                 // 2048 = bp(2) x g(64) x q(16)
    const int q = bx & 15, g = (bx >> 4) & 63, bp = bx >> 10;
    const bool colC = (g >= 16) && (g < 48);    // a in [128,384): column slabs
    const float* src0 = img + ((bp << 1) << 16);
    const float* src1 = img + (((bp << 1) | 1) << 16);

    const int   w   = tid & 255, sub = tid >> 8;  // angle uniform per wave
    const float xw  = (float)w - 127.5f;
    const int   rbase = (q << 4) - 1;           // slab-axis pairs rbase..rbase+18

    // ---- stage interleaved words for both batches (one band)
    if (!colC) {
        // row-mode: slab axis = image row. X' fastest -> 4 coalesced streams
        for (int u = tid; u < NCX * NRW; u += 512) {
            int Ri = u / NCX;                   // 0..17
            int Xp = u - Ri * NCX;              // 0..259
            int r0 = rbase + Ri;
            int c  = Xp - 2;
            float v00 = 0.f, v01 = 0.f, v10 = 0.f, v11 = 0.f;
            if ((unsigned)c < 256u) {
                if ((unsigned)r0 < 256u) {
                    v00 = src0[(r0 << 8) + c];
                    v10 = src1[(r0 << 8) + c];
                }
                if ((unsigned)(r0 + 1) < 256u) {
                    v01 = src0[((r0 + 1) << 8) + c];
                    v11 = src1[((r0 + 1) << 8) + c];
                }
            }
            uint2 pk;
            pk.x = __builtin_bit_cast(unsigned, __builtin_amdgcn_cvt_pkrtz(v00, v01));
            pk.y = __builtin_bit_cast(unsigned, __builtin_amdgcn_cvt_pkrtz(v10, v11));
            ((uint2*)ldsQ)[Xp * NR + Ri] = pk;
        }
    } else {
        // col-mode: slab axis = image column; Ri fastest so lanes read
        // ~19 consecutive floats per image row
        for (int u = tid; u < NCX * NRW; u += 512) {
            int Xp = u / NRW;                   // 0..259 (image row r = Xp-2)
            int Ri = u - Xp * NRW;              // 0..17  (image col c0 = rbase+Ri)
            int r  = Xp - 2;
            int c0 = rbase + Ri;
            float v00 = 0.f, v01 = 0.f, v10 = 0.f, v11 = 0.f;
            if ((unsigned)r < 256u) {
                const float* rp0 = src0 + (r << 8);
                const float* rp1 = src1 + (r << 8);
                if ((unsigned)c0 < 256u)       { v00 = rp0[c0];     v10 = rp1[c0]; }
                if ((unsigned)(c0 + 1) < 256u) { v01 = rp0[c0 + 1]; v11 = rp1[c0 + 1]; }
            }
            uint2 pk;
            pk.x = __builtin_bit_cast(unsigned, __builtin_amdgcn_cvt_pkrtz(v00, v01));
            pk.y = __builtin_bit_cast(unsigned, __builtin_amdgcn_cvt_pkrtz(v10, v11));
            ((uint2*)ldsQ)[Xp * NR + Ri] = pk;
        }
    }
    __syncthreads();

    // band [B0,B1) on the slab axis; adjacent q share identical floats
    const float B0 = (q == 0)  ? -1.0f  : (float)(q << 4);
    const float B1 = (q == 15) ? 256.0f : (float)((q << 4) + 16);

    float accA[4], accB[4];

#pragma unroll
    for (int k = 0; k < 4; ++k) {
        const int a = (g << 3) | (k << 1) | sub;
        const float th = (float)a * 6.1359231515425649e-3f;   // a*pi/512
        const float sth = __sinf(th), cth = __cosf(th);       // block-consistent
        const float Ax = fmaf(cth, xw, fmaf(sth, -127.5f, 127.5f));
        const float Ay = fmaf(-sth, xw, fmaf(cth, -127.5f, 127.5f));
        float cs, As, rs, Ar;                   // col coord / slab coord roles
        if (colC) { cs = cth; As = Ay; rs = sth; Ar = Ax; }
        else      { cs = sth; As = Ax; rs = cth; Ar = Ay; }

        // slab ownership: r(h)=Ar+h*rs in [B0,B1); |rs|>=0.707; exact
        // ceil/floor partition (adjacent q share identical boundary floats)
        const float invr = 1.0f / rs;
        const float tA = (B0 - Ar) * invr, tB = (B1 - Ar) * invr;
        int h0, h1;
        if (rs > 0.f) { h0 = (int)ceilf(tA);      h1 = (int)ceilf(tB) - 1; }
        else          { h0 = (int)floorf(tB) + 1; h1 = (int)floorf(tA);   }

        // col validity v(h)=As+h*cs in (-1,256); cs signed, may be ~0
        if (cs != 0.f) {
            const float invc = 1.0f / cs;
            float ta = (-1.0f - As) * invc, tb = (256.0f - As) * invc;
            ta = fmaxf(fminf(ta, 400.f), -400.f);
            tb = fmaxf(fminf(tb, 400.f), -400.f);
            if (cs > 0.f) { h0 = max(h0, (int)ceilf(ta));      h1 = min(h1, (int)ceilf(tb) - 1); }
            else          { h0 = max(h0, (int)floorf(tb) + 1); h1 = min(h1, (int)floorf(ta));   }
        } else if (As <= -1.f || As >= 256.f) {
            h1 = h0 - 1;
        }
        h0 = max(h0, 0); h1 = min(h1, 255);

        float a00 = 0.f, a01 = 0.f, a10 = 0.f, a11 = 0.f, a20 = 0.f, a21 = 0.f;
        if (h0 <= h1) {
            const float h0f = (float)h0;
            f32x2 pos0, st;
            pos0.x = fmaf(h0f, cs, As + 2.0f);           // col coord + 2
            pos0.y = fmaf(h0f, rs, Ar - (float)rbase);   // slab-local coord
            st.x = cs; st.y = rs;
            f32x2 pA = pos0, pB = pos0 + st, pC = pB + st;
            const f32x2 st3 = st + st + st;
            const int n = h1 - h0 + 1;                   // <= 24
            int i = 0;
            for (; i + 3 <= n; i += 3) {                 // triple h-chains
                SAMP2(pA, a00, a01);
                SAMP2(pB, a10, a11);
                SAMP2(pC, a20, a21);
                pA += st3; pB += st3; pC += st3;
            }
            if (i + 1 <= n) SAMP2(pA, a00, a01);
            if (i + 2 <= n) SAMP2(pB, a10, a11);
        }
        accA[k] = a00 + a10 + a20;
        accB[k] = a01 + a11 + a21;
    }

    // ---- fused reduction: coalesced atomics into acc[b][a][w] (w contiguous,
    // 256B per wave-atomic, 16 q-writers per cell)
    const int b0 = bp << 1;
#pragma unroll
    for (int k = 0; k < 4; ++k) {
        const int a = (g << 3) | (k << 1) | sub;
        atomicAdd(accW + ((((b0    ) << 9) | a) << 8) + w, accA[k]);
        atomicAdd(accW + ((((b0 + 1) << 9) | a) << 8) + w, accB[k]);
    }
}

// pure transpose: out[b][w][a] = acc[b][a][w]  (2MB -> 2MB)
__global__ __launch_bounds__(256) void transpose_out(const float* __restrict__ accW,
                                                     float* __restrict__ out) {
    __shared__ float s[32][33];
    const int bx = blockIdx.x;                  // 512 = b(4) x at(16) x wt(8)
    const int wt = bx & 7, at = (bx >> 3) & 15, b = bx >> 7;
    const int a0 = at << 5, w0 = wt << 5;
    const int wl = threadIdx.x & 31, r8 = threadIdx.x >> 5;
#pragma unroll
    for (int p = 0; p < 4; ++p) {
        int ar = r8 + (p << 3);
        s[ar][wl] = accW[(((b << 9) | (a0 + ar)) << 8) | (w0 + wl)];  // coalesced in w
    }
    __syncthreads();
#pragma unroll
    for (int p = 0; p < 4; ++p) {
        int wr = r8 + (p << 3);
        out[(b << 17) | ((w0 + wr) << 9) | (a0 + wl)] = s[wl][wr];    // coalesced in a
    }
}

extern "C" void kernel_launch(void* const* d_in, const int* in_sizes, int n_in,
                              void* d_out, int out_size, void* d_ws, size_t ws_size,
                              hipStream_t stream) {
    const float* img = (const float*)d_in[0];
    float* out  = (float*)d_out;
    float* accW = (float*)d_ws;                 // 2 MB: acc[b][a][w]
    hipMemsetAsync(accW, 0, (size_t)4 * 512 * 256 * 4, stream);
    radon_k      <<<dim3(2048), dim3(512), 0, stream>>>(img, accW);
    transpose_out<<<dim3(512),  dim3(256), 0, stream>>>(accW, out);
}